// Round 21
// baseline (154.793 us; speedup 1.0000x reference)
//
#include <hip/hip_runtime.h>
#include <math.h>

#define N_QUBITS 24
#define N_BLOCKS 4
#define NSTATE (1 << N_QUBITS)

// Qubit q <-> flat bit (23-q). Per block: RY(0); q=1..23: RY(q); CNOT(q-1,q).
// 5-dispatch schedule (span-repacked, 576 MB total):
//  F: b0 analytic + b1 q0..14   span {e9..23}            -> out  (write-only)
//  A: b1 q15..23 + b2 q0..5     span {e0..8}u{e18..23}   out -> ws
//  B: b2 q6..20                 span {e3..17} (e18 diag) ws -> out
//  C: b2 q21..23 + b3 q0..8     span {e0..5}u{e15..23}   out -> ws
//  D: b3 q9..23 + SQUARE        span {e0..14} (e15 diag) ws -> out (std layout)
// Each interface shares 6 bits = lane set of writer AND reader -> every global
// access is 256B-contiguous per wave instr. All kernels 1024 thr x 32 regs.

// ---- VALU lane-exchange primitives (R17/R20-proven) ----
template <int CTRL>
__device__ __forceinline__ float dpp_mov(float v) {
    return __int_as_float(__builtin_amdgcn_update_dpp(
        __float_as_int(v), __float_as_int(v), CTRL, 0xF, 0xF, false));
}
template <int MASK>
__device__ __forceinline__ float xor_lanes(float v, int lane) {
    if constexpr (MASK == 1)       return dpp_mov<0xB1>(v);   // quad_perm [1,0,3,2]
    else if constexpr (MASK == 2)  return dpp_mov<0x4E>(v);   // quad_perm [2,3,0,1]
    else if constexpr (MASK == 4) {
        float lo = dpp_mov<0x114>(v);   // row_shr:4 -> dst[i] = src[i-4]
        float hi = dpp_mov<0x104>(v);   // row_shl:4 -> dst[i] = src[i+4]
        return (lane & 4) ? lo : hi;
    }
    else if constexpr (MASK == 8)  return dpp_mov<0x128>(v);  // row_ror:8 == xor 8
    else                           return __shfl_xor(v, MASK);
}

// ---- 32-reg gate helpers (proven) ----
template <int B>
__device__ __forceinline__ void pair_bit32(float (&a)[32], float s, float c, int swap) {
#pragma unroll
    for (int g = 0; g < 16; ++g) {
        int r0 = ((g >> B) << (B + 1)) | (g & ((1 << B) - 1));
        int r1 = r0 | (1 << B);
        float v0 = a[r0], v1 = a[r1];
        float o0 = c * v0 - s * v1;
        float o1 = s * v0 + c * v1;
        a[r0] = swap ? o1 : o0;
        a[r1] = swap ? o0 : o1;
    }
}
template <int BT>
__device__ __forceinline__ void quad_gate32(float (&a)[32], float s, float c) {
#pragma unroll
    for (int g = 0; g < 8; ++g) {
        int lo  = g & ((1 << BT) - 1);
        int r00 = ((g >> BT) << (BT + 2)) | lo;
        int r01 = r00 | (1 << BT);
        int r10 = r00 | (2 << BT);
        int r11 = r00 | (3 << BT);
        float v00 = a[r00], v01 = a[r01], v10 = a[r10], v11 = a[r11];
        a[r00] = c * v00 - s * v01;
        a[r01] = s * v00 + c * v01;
        a[r10] = s * v10 + c * v11;
        a[r11] = c * v10 - s * v11;
    }
}
// RY+CNOT with tgt = reg bit 4, ctrl = reg bit 0.
__device__ __forceinline__ void pair_ctrl_reg0(float (&a)[32], float s, float c) {
#pragma unroll
    for (int g = 0; g < 16; ++g) {
        float v0 = a[g], v1 = a[g | 16];
        float o0 = c * v0 - s * v1;
        float o1 = s * v0 + c * v1;
        if (g & 1) { a[g] = o1; a[g | 16] = o0; }
        else       { a[g] = o0; a[g | 16] = o1; }
    }
}
// Fused RY+CNOT lane gate: tgt = lane bit of MASK, ctrl = lane bit of 2*MASK.
template <int MASK>
__device__ __forceinline__ void lane_gate32(float (&a)[32], float s, float c, int lane) {
    const int tau = (lane & MASK) ? 1 : 0;
    const int gam = (lane & (MASK << 1)) ? 1 : 0;
    const float A = gam ? (tau ? -s : s) : c;
    const float B = gam ? c : (tau ? s : -s);
#pragma unroll
    for (int r = 0; r < 32; ++r) {
        float p = xor_lanes<MASK>(a[r], lane);
        a[r] = A * a[r] + B * p;
    }
}
// RY-only lane gate on lane bit of MASK.
template <int MASK>
__device__ __forceinline__ void lane_ry32(float (&a)[32], float s, float c, int lane) {
    const int tau = (lane & MASK) ? 1 : 0;
    const float A = c, B = tau ? s : -s;
#pragma unroll
    for (int r = 0; r < 32; ++r) {
        float p = xor_lanes<MASK>(a[r], lane);
        a[r] = A * a[r] + B * p;
    }
}
// Lane gate, tgt = lane bit of MASK, ctrl = reg bit 0.
template <int MASK>
__device__ __forceinline__ void lane_gate32_regctrl(float (&a)[32], float s, float c,
                                                    int lane, int tau) {
    const float A0 = c,            B0 = tau ? s : -s;
    const float A1 = tau ? -s : s, B1 = c;
#pragma unroll
    for (int r = 0; r < 32; ++r) {
        float p = xor_lanes<MASK>(a[r], lane);
        float A = (r & 1) ? A1 : A0;
        float B = (r & 1) ? B1 : B0;
        a[r] = A * a[r] + B * p;
    }
}

// Identity chunked transpose (chunk = reg bit 4): swap reg bits0..3 <-> w.
// lds idx: lane | (w<<6) | (j<<10). Proven pattern (R13..R20 T1s).
#define IDT_TRANSPOSE(a, lds, lane, w)                                   \
    _Pragma("unroll")                                                    \
    for (int x = 0; x < 2; ++x) {                                        \
        __syncthreads();                                                 \
        _Pragma("unroll")                                                \
        for (int j = 0; j < 16; ++j)                                     \
            lds[(lane) | ((w) << 6) | (j << 10)] = a[(x << 4) | j];      \
        __syncthreads();                                                 \
        _Pragma("unroll")                                                \
        for (int m = 0; m < 16; ++m)                                     \
            a[(x << 4) | m] = lds[(lane) | (m << 6) | ((w) << 10)];      \
    }

// =========================== Kernel F ===========================
// b0 analytic + b1 q0..14. Span {e9..23}; blk = e0..8. No global reads.
// L0: lane=e18..23, w=e14..17, regs=e9..13. amp = f10[w|(lane<<4)] * g.
// q0..5 lane gates. T_F (chunk e13@r4): L1 regs=(e14..17,e13), w=e9..12.
// q6..10. T2_F (chunk e13): L2 regs=(e9..12,e13), w=e14..17. q11..14.
// Write hF: [0..5]=e18..23, [6..9]=e14..17, [10..13]=e9..12, [14]=e13.
__global__ __launch_bounds__(1024, 2)
void kernF(float* __restrict__ dst, const float* __restrict__ angles) {
    __shared__ float lds[16384];
    __shared__ float s0[24], c0[24], s1[15], c1[15];
    const int tid  = threadIdx.x;
    const int lane = tid & 63;
    const int w    = tid >> 6;
    const int blk  = blockIdx.x;                 // e0..8

    if (tid < 24) {
        float s, c; sincosf(0.5f * angles[tid], &s, &c);
        s0[tid] = s; c0[tid] = c;
    } else if (tid >= 32 && tid < 47) {
        float s, c; sincosf(0.5f * angles[24 + (tid - 32)], &s, &c);
        s1[tid - 32] = s; c1[tid - 32] = c;
    }

    // f10 sim (b0 q0..9) in lds[0..1023]; f bit k = e(14+k), qubit q -> bit 9-q.
    float* f = lds;
    f[tid] = 0.0f;
    __syncthreads();
    if (tid == 0) f[0] = 1.0f;
    __syncthreads();
    if (tid < 512) {
        float s = s0[0], c = c0[0];
        float v0 = f[tid], v1 = f[tid | 512];
        f[tid] = c * v0 - s * v1;
        f[tid | 512] = s * v0 + c * v1;
    }
    __syncthreads();
    for (int q = 1; q <= 9; ++q) {
        int bt = 9 - q;
        if (tid < 256) {
            float s = s0[q], c = c0[q];
            int lo  = tid & ((1 << bt) - 1);
            int r00 = ((tid >> bt) << (bt + 2)) | lo;
            int r01 = r00 | (1 << bt);
            int r10 = r00 | (2 << bt);
            int r11 = r00 | (3 << bt);
            float v00 = f[r00], v01 = f[r01], v10 = f[r10], v11 = f[r11];
            f[r00] = c * v00 - s * v01;
            f[r01] = s * v00 + c * v01;
            f[r10] = s * v10 + c * v11;
            f[r11] = c * v10 - s * v11;
        }
        __syncthreads();
    }

    // g chain: pairs (e_j, e_{j+1}), factor for qubit 23-j: x? s0 : c0.
    float gfix = 1.0f;
#pragma unroll
    for (int j = 0; j < 8; ++j) {                // q23..q16: blk-only bits
        int x = ((blk >> j) ^ (blk >> (j + 1))) & 1;
        gfix *= x ? s0[23 - j] : c0[23 - j];
    }
    const float fval = f[w | (lane << 4)];       // f10 index (per-thread const)
    const int b8 = (blk >> 8) & 1;
    const int w0 = w & 1;                        // e14

    float a[32];
#pragma unroll
    for (int r = 0; r < 32; ++r) {
        const int r0 = r & 1, r1 = (r >> 1) & 1, r2 = (r >> 2) & 1,
                  r3 = (r >> 3) & 1, r4 = (r >> 4) & 1;
        float g = gfix;
        g *= (b8 ^ r0) ? s0[15] : c0[15];        // (e8,e9)
        g *= (r0 ^ r1) ? s0[14] : c0[14];
        g *= (r1 ^ r2) ? s0[13] : c0[13];
        g *= (r2 ^ r3) ? s0[12] : c0[12];
        g *= (r3 ^ r4) ? s0[11] : c0[11];
        g *= (r4 ^ w0) ? s0[10] : c0[10];        // (e13,e14)
        a[r] = fval * g;
    }

    // b1 q0..5: lane gates on e23..e18 (lane bit 5..0)
    lane_ry32<32>(a, s1[0], c1[0], lane);        // q0 RY e23
    lane_gate32<16>(a, s1[1], c1[1], lane);      // q1
    lane_gate32<8>(a, s1[2], c1[2], lane);       // q2
    lane_gate32<4>(a, s1[3], c1[3], lane);       // q3
    lane_gate32<2>(a, s1[4], c1[4], lane);       // q4
    lane_gate32<1>(a, s1[5], c1[5], lane);       // q5

    IDT_TRANSPOSE(a, lds, lane, w)               // T_F: regs <-> w (chunk e13)

    // L1: regs=(e14,e15,e16,e17,e13@4), w=e9..12, lane=e18..23
    pair_bit32<3>(a, s1[6], c1[6], lane & 1);    // q6: tgt e17, ctrl e18
    quad_gate32<2>(a, s1[7], c1[7]);             // q7: tgt e16 ctrl e17
    quad_gate32<1>(a, s1[8], c1[8]);             // q8
    quad_gate32<0>(a, s1[9], c1[9]);             // q9: tgt e14 ctrl e15
    pair_ctrl_reg0(a, s1[10], c1[10]);           // q10: tgt e13(r4), ctrl e14(r0)

    IDT_TRANSPOSE(a, lds, lane, w)               // T2_F: regs <-> w (chunk e13)

    // L2: regs=(e9..12, e13@4), w=e14..17
    quad_gate32<3>(a, s1[11], c1[11]);           // q11: tgt e12 ctrl e13
    quad_gate32<2>(a, s1[12], c1[12]);           // q12
    quad_gate32<1>(a, s1[13], c1[13]);           // q13
    quad_gate32<0>(a, s1[14], c1[14]);           // q14: tgt e9 ctrl e10

    // write hF
#pragma unroll
    for (int m = 0; m < 32; ++m)
        dst[((size_t)blk << 15) | lane | (w << 6) | ((m & 15) << 10)
            | ((m >> 4) << 14)] = a[m];
}

// =========================== Kernel A ===========================
// b1 q15..23 + b2 q0..5. Span {e0..8}u{e18..23}; blk = e9..17.
// L0: lane=e18..23, regs=(e5..8,e0@4), w=e1..4. Read hF.
// q15..18. T_A (chunk e0@r4): L1 regs=(e1..4,e0), w=e5..8. q19..23.
// b2 q0..5 lane gates. T_A2 (swizzled, chunk e0): L2 lane=e3..8,
// regs=(e1,e2,e18,e19,e0@4), w=e20..23. Write hA: [0..5]=e3..8,[6]=e0,
// [7]=e1,[8]=e2,[9]=e18,[10]=e19,[11..14]=e20..23.
__global__ __launch_bounds__(1024, 2)
void kernA(const float* __restrict__ src, float* __restrict__ dst,
           const float* __restrict__ angles) {
    __shared__ float lds[16384];
    __shared__ float scs[15], scc[15];
    const int tid  = threadIdx.x;
    const int lane = tid & 63;
    const int w    = tid >> 6;
    const int blk  = blockIdx.x;                 // e9..17

    if (tid < 9) {          // b1 q15..23
        float s, c; sincosf(0.5f * angles[24 + 15 + tid], &s, &c);
        scs[tid] = s; scc[tid] = c;
    } else if (tid >= 16 && tid < 22) {          // b2 q0..5
        float s, c; sincosf(0.5f * angles[48 + (tid - 16)], &s, &c);
        scs[9 + tid - 16] = s; scc[9 + tid - 16] = c;
    }

    float a[32];
    // read hF: Fblk = e0..8 from (r,w); hF rest from Ablk
    const int hi4 = blk >> 5, lo4 = blk & 15, b13 = (blk >> 4) & 1;
#pragma unroll
    for (int r = 0; r < 32; ++r) {
        int Fblk = ((r >> 4) & 1) | (w << 1) | ((r & 15) << 5);
        a[r] = src[((size_t)Fblk << 15) | lane | (hi4 << 6) | (lo4 << 10)
                   | (b13 << 14)];
    }
    __syncthreads();

    // L0: regs=(e5,e6,e7,e8,e0@4), w=e1..4
    pair_bit32<3>(a, scs[0], scc[0], blk & 1);   // q15: tgt e8, ctrl e9 (diag)
    quad_gate32<2>(a, scs[1], scc[1]);           // q16: tgt e7 ctrl e8
    quad_gate32<1>(a, scs[2], scc[2]);           // q17
    quad_gate32<0>(a, scs[3], scc[3]);           // q18: tgt e5 ctrl e6

    IDT_TRANSPOSE(a, lds, lane, w)               // T_A (chunk e0@r4)

    // L1: regs=(e1..4, e0@4), w=e5..8
    pair_bit32<3>(a, scs[4], scc[4], w & 1);     // q19: tgt e4, ctrl e5
    quad_gate32<2>(a, scs[5], scc[5]);           // q20
    quad_gate32<1>(a, scs[6], scc[6]);           // q21
    quad_gate32<0>(a, scs[7], scc[7]);           // q22: tgt e1 ctrl e2
    pair_ctrl_reg0(a, scs[8], scc[8]);           // q23: tgt e0(r4), ctrl e1(r0)

    // b2 q0..5: lane gates on e23..e18
    lane_ry32<32>(a, scs[9], scc[9], lane);      // q0 RY e23
    lane_gate32<16>(a, scs[10], scc[10], lane);  // q1
    lane_gate32<8>(a, scs[11], scc[11], lane);   // q2
    lane_gate32<4>(a, scs[12], scc[12], lane);   // q3
    lane_gate32<2>(a, scs[13], scc[13], lane);   // q4
    lane_gate32<1>(a, scs[14], scc[14], lane);   // q5

    // T_A2 + write (chunk by e0 = reg bit 4): swizzled LDS
    // h: [0..4]=(e18..22)^(e3..7), [5]=e23, [6]=e8, [7..11]=e3..7, [12]=e1, [13]=e2
#pragma unroll
    for (int x = 0; x < 2; ++x) {
        __syncthreads();
#pragma unroll
        for (int jj = 0; jj < 16; ++jj) {        // regs (x<<4)|jj; jj = e1..4
            int E37 = (jj >> 2) | ((w & 7) << 2);
            int h = ((lane & 31) ^ E37) | (((lane >> 5) & 1) << 5)
                  | (((w >> 3) & 1) << 6) | (E37 << 7)
                  | ((jj & 1) << 12) | (((jj >> 1) & 1) << 13);
            lds[h] = a[(x << 4) | jj];
        }
        __syncthreads();
#pragma unroll
        for (int mm = 0; mm < 16; ++mm) {        // L2 regs: mm=(e1,e2,e18,e19)
            // read as L2 thread: lane' = e3..8 (reuse lane), w' = e20..23 (reuse w)
            int E1822 = ((mm >> 2) & 1) | (((mm >> 3) & 1) << 1) | ((w & 7) << 2);
            int h = (E1822 ^ (lane & 31)) | (((w >> 3) & 1) << 5)
                  | (((lane >> 5) & 1) << 6) | ((lane & 31) << 7)
                  | ((mm & 1) << 12) | (((mm >> 1) & 1) << 13);
            float v = lds[h];
            // write hA directly
            dst[((size_t)blk << 15) | lane | (x << 6) | ((mm & 1) << 7)
                | (((mm >> 1) & 1) << 8) | (((mm >> 2) & 1) << 9)
                | (((mm >> 3) & 1) << 10) | (w << 11)] = v;
        }
    }
}

// =========================== Kernel B ===========================
// b2 q6..20. Span {e3..17}; blk: [0..2]=e0..2, [3]=e18, [4]=e19, [5..8]=e20..23.
// L0: lane=e3..8, w=e9..12, regs=(e13..17). Read hA.
// q6..10. T1_B (chunk e17@r4): L1 regs=(e9..12,e17), w=e13..16. q11..20.
// T_B2 (swizzled, chunk e9@r0): L2 lane=(e3,e4,e5,e15,e16,e17),
// regs=(e9..12,e13@4), w=(e6,e7,e8,e14). Write hB: [0..5]=lane',[6..8]=e6..8,
// [9..12]=e9..12, [13]=e13, [14]=e14.
__global__ __launch_bounds__(1024, 2)
void kernB(const float* __restrict__ src, float* __restrict__ dst,
           const float* __restrict__ angles) {
    __shared__ float lds[16384];
    __shared__ float scs[15], scc[15];
    const int tid  = threadIdx.x;
    const int lane = tid & 63;
    const int w    = tid >> 6;
    const int blk  = blockIdx.x;

    if (tid < 15) {                              // b2 q6..20
        float s, c; sincosf(0.5f * angles[48 + 6 + tid], &s, &c);
        scs[tid] = s; scc[tid] = c;
    }

    float a[32];
    const int fixedA = ((blk & 1) << 6) | (((blk >> 1) & 1) << 7)
                     | (((blk >> 2) & 1) << 8) | (((blk >> 3) & 1) << 9)
                     | (((blk >> 4) & 1) << 10) | ((blk >> 5) << 11);
#pragma unroll
    for (int r = 0; r < 32; ++r) {
        int Ablk = w | (r << 4);                 // e9..12=w, e13..17=r
        a[r] = src[((size_t)Ablk << 15) | lane | fixedA];
    }
    __syncthreads();

    // L0: regs=(e13..17)
    pair_bit32<4>(a, scs[0], scc[0], (blk >> 3) & 1);  // q6: tgt e17, ctrl e18 diag
    quad_gate32<3>(a, scs[1], scc[1]);           // q7: tgt e16 ctrl e17
    quad_gate32<2>(a, scs[2], scc[2]);           // q8
    quad_gate32<1>(a, scs[3], scc[3]);           // q9
    quad_gate32<0>(a, scs[4], scc[4]);           // q10: tgt e13 ctrl e14

    IDT_TRANSPOSE(a, lds, lane, w)               // T1_B (chunk e17@r4)

    // L1: regs=(e9..12, e17@4), w=e13..16
    pair_bit32<3>(a, scs[5], scc[5], w & 1);     // q11: tgt e12, ctrl e13
    quad_gate32<2>(a, scs[6], scc[6]);           // q12
    quad_gate32<1>(a, scs[7], scc[7]);           // q13
    quad_gate32<0>(a, scs[8], scc[8]);           // q14: tgt e9 ctrl e10
    lane_gate32_regctrl<32>(a, scs[9], scc[9], lane, (lane >> 5) & 1); // q15: tgt e8, ctrl e9(r0)
    lane_gate32<16>(a, scs[10], scc[10], lane);  // q16: tgt e7 ctrl e8
    lane_gate32<8>(a, scs[11], scc[11], lane);   // q17
    lane_gate32<4>(a, scs[12], scc[12], lane);   // q18
    lane_gate32<2>(a, scs[13], scc[13], lane);   // q19
    lane_gate32<1>(a, scs[14], scc[14], lane);   // q20: tgt e3 ctrl e4

    // T_B2 + write (chunk by e9 = reg bit 0): swizzled
    // h: [0..2]=e3..5, [3]=e6^e15, [4]=e7^e16, [5]=e8, [6]=e15, [7]=e16,
    //    [8]=e17, [9..11]=e10..12, [12]=e13, [13]=e14
#pragma unroll
    for (int x = 0; x < 2; ++x) {
        __syncthreads();
#pragma unroll
        for (int jj = 0; jj < 16; ++jj) {        // regs (jj<<1)|x; jj: e10..12, e17
            int h = (lane & 7)
                  | (((((lane >> 3) & 1)) ^ ((w >> 2) & 1)) << 3)
                  | (((((lane >> 4) & 1)) ^ ((w >> 3) & 1)) << 4)
                  | (((lane >> 5) & 1) << 5)
                  | (((w >> 2) & 1) << 6) | (((w >> 3) & 1) << 7)
                  | (((jj >> 3) & 1) << 8) | ((jj & 7) << 9)
                  | ((w & 1) << 12) | (((w >> 1) & 1) << 13);
            lds[h] = a[(jj << 1) | x];
        }
        __syncthreads();
#pragma unroll
        for (int mm = 0; mm < 16; ++mm) {        // L2 regs (mm<<1)|x; mm: e10..12, e13
            // L2 thread: lane' = (e3,e4,e5,e15,e16,e17) [reuse lane], w' = (e6,e7,e8,e14) [reuse w]
            int h = (lane & 7)
                  | ((((w & 1)) ^ ((lane >> 3) & 1)) << 3)
                  | (((((w >> 1) & 1)) ^ ((lane >> 4) & 1)) << 4)
                  | (((w >> 2) & 1) << 5)
                  | (((lane >> 3) & 1) << 6) | (((lane >> 4) & 1) << 7)
                  | (((lane >> 5) & 1) << 8) | ((mm & 7) << 9)
                  | (((mm >> 3) & 1) << 12) | (((w >> 3) & 1) << 13);
            float v = lds[h];
            dst[((size_t)blk << 15) | lane | ((w & 7) << 6) | (x << 9)
                | ((mm & 7) << 10) | (((mm >> 3) & 1) << 13)
                | (((w >> 3) & 1) << 14)] = v;
        }
    }
}

// =========================== Kernel C ===========================
// b2 q21..23 + b3 q0..8. Span {e0..5}u{e15..23}; blk = e6..14.
// L0: lane=(e3,e4,e5,e15,e16,e17), regs=(e0,e1,e2,e18,e19), w=e20..23. Read hB.
// q21..23. T_C (chunk e19@r4): L1 regs=(e20..23,e19), w=(e0,e1,e2,e18). q0..4.
// T_C3 (swizzled, chunk e19@r4): L2 lane=e0..5, regs=(e15..18,e19@4), w=e20..23.
// q5..8. Write hC: [0..5]=e0..5, [6..14]=e15..23.
__global__ __launch_bounds__(1024, 2)
void kernC(const float* __restrict__ src, float* __restrict__ dst,
           const float* __restrict__ angles) {
    __shared__ float lds[16384];
    __shared__ float scs[12], scc[12];
    const int tid  = threadIdx.x;
    const int lane = tid & 63;
    const int w    = tid >> 6;
    const int blk  = blockIdx.x;                 // e6..14

    if (tid < 3) {                               // b2 q21..23
        float s, c; sincosf(0.5f * angles[48 + 21 + tid], &s, &c);
        scs[tid] = s; scc[tid] = c;
    } else if (tid >= 8 && tid < 17) {           // b3 q0..8
        float s, c; sincosf(0.5f * angles[72 + (tid - 8)], &s, &c);
        scs[3 + tid - 8] = s; scc[3 + tid - 8] = c;
    }

    float a[32];
    const int fixedB = ((blk & 7) << 6) | (((blk >> 3) & 15) << 9)
                     | (((blk >> 7) & 1) << 13) | (((blk >> 8) & 1) << 14);
#pragma unroll
    for (int r = 0; r < 32; ++r) {
        int Bblk = (r & 31) | (w << 5);          // e0..2,e18,e19 = r; e20..23 = w
        a[r] = src[((size_t)Bblk << 15) | lane | fixedB];
    }
    __syncthreads();

    // L0: regs=(e0,e1,e2,e18,e19)
    pair_bit32<2>(a, scs[0], scc[0], lane & 1);  // q21: tgt e2, ctrl e3 (lane0)
    quad_gate32<1>(a, scs[1], scc[1]);           // q22: tgt e1 ctrl e2
    quad_gate32<0>(a, scs[2], scc[2]);           // q23: tgt e0 ctrl e1

    IDT_TRANSPOSE(a, lds, lane, w)               // T_C (chunk e19@r4)

    // L1: regs=(e20..23, e19@4), w=(e0,e1,e2,e18)
    pair_bit32<3>(a, scs[3], scc[3], 0);         // b3 q0: RY tgt e23
    quad_gate32<2>(a, scs[4], scc[4]);           // q1: tgt e22 ctrl e23
    quad_gate32<1>(a, scs[5], scc[5]);           // q2
    quad_gate32<0>(a, scs[6], scc[6]);           // q3: tgt e20 ctrl e21
    pair_ctrl_reg0(a, scs[7], scc[7]);           // q4: tgt e19(r4), ctrl e20(r0)

    // T_C3 (chunk e19 = reg bit 4): swizzled
    // h: [0..2]=e3..5, [3]=e15^e0, [4]=e16^e1, [5]=e17, [6]=e15, [7]=e16,
    //    [8]=e18, [9]=e2, [10..13]=e20..23
#pragma unroll
    for (int x = 0; x < 2; ++x) {
        __syncthreads();
#pragma unroll
        for (int jj = 0; jj < 16; ++jj) {        // regs (x<<4)|jj; jj = e20..23
            int h = (lane & 7)
                  | ((((lane >> 3) & 1) ^ (w & 1)) << 3)
                  | ((((lane >> 4) & 1) ^ ((w >> 1) & 1)) << 4)
                  | (((lane >> 5) & 1) << 5)
                  | (((lane >> 3) & 1) << 6) | (((lane >> 4) & 1) << 7)
                  | (((w >> 3) & 1) << 8) | (((w >> 2) & 1) << 9)
                  | (jj << 10);
            lds[h] = a[(x << 4) | jj];
        }
        __syncthreads();
#pragma unroll
        for (int mm = 0; mm < 16; ++mm) {        // L2 regs (x<<4)|mm; mm = e15..18
            // L2 thread: lane' = e0..5 [reuse lane], w' = e20..23 [reuse w]
            int h = ((lane >> 3) & 7)
                  | (((mm & 1) ^ (lane & 1)) << 3)
                  | ((((mm >> 1) & 1) ^ ((lane >> 1) & 1)) << 4)
                  | (((mm >> 2) & 1) << 5)
                  | ((mm & 1) << 6) | (((mm >> 1) & 1) << 7)
                  | (((mm >> 3) & 1) << 8) | (((lane >> 2) & 1) << 9)
                  | (w << 10);
            a[(x << 4) | mm] = lds[h];
        }
    }

    // L2: regs=(e15,e16,e17,e18, e19@4), w=e20..23, lane=e0..5
    quad_gate32<3>(a, scs[8], scc[8]);           // q5: tgt e18 ctrl e19
    quad_gate32<2>(a, scs[9], scc[9]);           // q6: tgt e17 ctrl e18
    quad_gate32<1>(a, scs[10], scc[10]);         // q7
    quad_gate32<0>(a, scs[11], scc[11]);         // q8: tgt e15 ctrl e16

    // write hC
#pragma unroll
    for (int m = 0; m < 32; ++m)
        dst[((size_t)blk << 15) | lane | ((m & 15) << 6) | ((m >> 4) << 10)
            | (w << 11)] = a[m];
}

// =========================== Kernel D ===========================
// b3 q9..23 + SQUARE. Span {e0..14}; blk = e15..23. Read hC; write STANDARD.
// L0: lane=e0..5, w=e6..9, regs=e10..14. q9..13.
// T1_D (chunk e14@r4): L1 regs=(e6..9,e14), w=e10..13. q14..23 + SQUARE.
__global__ __launch_bounds__(1024, 2)
void kernD(const float* __restrict__ src, float* __restrict__ dst,
           const float* __restrict__ angles) {
    __shared__ float lds[16384];
    __shared__ float scs[15], scc[15];
    const int tid  = threadIdx.x;
    const int lane = tid & 63;
    const int w    = tid >> 6;
    const int blk  = blockIdx.x;                 // e15..23

    if (tid < 15) {                              // b3 q9..23
        float s, c; sincosf(0.5f * angles[72 + 9 + tid], &s, &c);
        scs[tid] = s; scc[tid] = c;
    }

    float a[32];
#pragma unroll
    for (int r = 0; r < 32; ++r) {
        int Cblk = w | (r << 4);                 // e6..9=w, e10..14=r
        a[r] = src[((size_t)Cblk << 15) | lane | (blk << 6)];
    }
    __syncthreads();

    // L0: regs=(e10..14)
    pair_bit32<4>(a, scs[0], scc[0], blk & 1);   // q9: tgt e14, ctrl e15 diag
    quad_gate32<3>(a, scs[1], scc[1]);           // q10: tgt e13 ctrl e14
    quad_gate32<2>(a, scs[2], scc[2]);           // q11
    quad_gate32<1>(a, scs[3], scc[3]);           // q12
    quad_gate32<0>(a, scs[4], scc[4]);           // q13: tgt e10 ctrl e11

    IDT_TRANSPOSE(a, lds, lane, w)               // T1_D (chunk e14@r4)

    // L1: regs=(e6..9, e14@4), w=e10..13
    pair_bit32<3>(a, scs[5], scc[5], w & 1);     // q14: tgt e9, ctrl e10
    quad_gate32<2>(a, scs[6], scc[6]);           // q15: tgt e8 ctrl e9
    quad_gate32<1>(a, scs[7], scc[7]);           // q16
    quad_gate32<0>(a, scs[8], scc[8]);           // q17: tgt e6 ctrl e7
    lane_gate32_regctrl<32>(a, scs[9], scc[9], lane, (lane >> 5) & 1); // q18: tgt e5, ctrl e6(r0)
    lane_gate32<16>(a, scs[10], scc[10], lane);  // q19
    lane_gate32<8>(a, scs[11], scc[11], lane);   // q20
    lane_gate32<4>(a, scs[12], scc[12], lane);   // q21
    lane_gate32<2>(a, scs[13], scc[13], lane);   // q22
    lane_gate32<1>(a, scs[14], scc[14], lane);   // q23

#pragma unroll
    for (int r = 0; r < 32; ++r) a[r] *= a[r];   // SQUARE

    // write STANDARD: e0..5=lane, e6..9=m0..3, e10..13=w, e14=m4, e15..23=blk
#pragma unroll
    for (int m = 0; m < 32; ++m)
        dst[((size_t)blk << 15) | ((m >> 4) << 14) | (w << 10) | ((m & 15) << 6)
            | lane] = a[m];
}

extern "C" void kernel_launch(void* const* d_in, const int* in_sizes, int n_in,
                              void* d_out, int out_size, void* d_ws, size_t ws_size,
                              hipStream_t stream) {
    const float* angles = (const float*)d_in[0];
    float* out = (float*)d_out;
    float* ws  = (float*)d_ws;

    kernF<<<512, 1024, 0, stream>>>(out, angles);        // -> out (hF)
    kernA<<<512, 1024, 0, stream>>>(out, ws, angles);    // out -> ws (hA)
    kernB<<<512, 1024, 0, stream>>>(ws, out, angles);    // ws -> out (hB)
    kernC<<<512, 1024, 0, stream>>>(out, ws, angles);    // out -> ws (hC)
    kernD<<<512, 1024, 0, stream>>>(ws, out, angles);    // ws -> out (std)
}

// Round 22
// 153.774 us; speedup vs baseline: 1.0066x; 1.0066x over previous
//
#include <hip/hip_runtime.h>
#include <math.h>

#define N_QUBITS 24
#define N_BLOCKS 4
#define NSTATE (1 << N_QUBITS)

// Qubit q <-> flat bit (23-q). Per block: RY(0); q=1..23: RY(q); CNOT(q-1,q).
// 5-dispatch schedule (span-repacked, 576 MB total):
//  F: b0 analytic + b1 q0..14   span {e9..23}            -> out  (write-only)
//  A: b1 q15..23 + b2 q0..5     span {e0..8}u{e18..23}   out -> ws
//  B: b2 q6..20                 span {e3..17} (e18 diag) ws -> out
//  C: b2 q21..23 + b3 q0..8     span {e0..5}u{e15..23}   out -> ws
//  D: b3 q9..23 + SQUARE        span {e0..14} (e15 diag) ws -> out (std layout)
// R22: A/B/C use __launch_bounds__(1024) (128-VGPR cap, 16 waves/CU) — the
// (1024,2) 64-VGPR cap spilled a[32] in kernB (R21: VGPR=36, 46.5us).
// Swizzled-transpose address constants hoisted out of the unrolled loops.

// ---- VALU lane-exchange primitives (R17/R20-proven) ----
template <int CTRL>
__device__ __forceinline__ float dpp_mov(float v) {
    return __int_as_float(__builtin_amdgcn_update_dpp(
        __float_as_int(v), __float_as_int(v), CTRL, 0xF, 0xF, false));
}
template <int MASK>
__device__ __forceinline__ float xor_lanes(float v, int lane) {
    if constexpr (MASK == 1)       return dpp_mov<0xB1>(v);   // quad_perm [1,0,3,2]
    else if constexpr (MASK == 2)  return dpp_mov<0x4E>(v);   // quad_perm [2,3,0,1]
    else if constexpr (MASK == 4) {
        float lo = dpp_mov<0x114>(v);   // row_shr:4 -> dst[i] = src[i-4]
        float hi = dpp_mov<0x104>(v);   // row_shl:4 -> dst[i] = src[i+4]
        return (lane & 4) ? lo : hi;
    }
    else if constexpr (MASK == 8)  return dpp_mov<0x128>(v);  // row_ror:8 == xor 8
    else                           return __shfl_xor(v, MASK);
}

// ---- 32-reg gate helpers (proven) ----
template <int B>
__device__ __forceinline__ void pair_bit32(float (&a)[32], float s, float c, int swap) {
#pragma unroll
    for (int g = 0; g < 16; ++g) {
        int r0 = ((g >> B) << (B + 1)) | (g & ((1 << B) - 1));
        int r1 = r0 | (1 << B);
        float v0 = a[r0], v1 = a[r1];
        float o0 = c * v0 - s * v1;
        float o1 = s * v0 + c * v1;
        a[r0] = swap ? o1 : o0;
        a[r1] = swap ? o0 : o1;
    }
}
template <int BT>
__device__ __forceinline__ void quad_gate32(float (&a)[32], float s, float c) {
#pragma unroll
    for (int g = 0; g < 8; ++g) {
        int lo  = g & ((1 << BT) - 1);
        int r00 = ((g >> BT) << (BT + 2)) | lo;
        int r01 = r00 | (1 << BT);
        int r10 = r00 | (2 << BT);
        int r11 = r00 | (3 << BT);
        float v00 = a[r00], v01 = a[r01], v10 = a[r10], v11 = a[r11];
        a[r00] = c * v00 - s * v01;
        a[r01] = s * v00 + c * v01;
        a[r10] = s * v10 + c * v11;
        a[r11] = c * v10 - s * v11;
    }
}
// RY+CNOT with tgt = reg bit 4, ctrl = reg bit 0.
__device__ __forceinline__ void pair_ctrl_reg0(float (&a)[32], float s, float c) {
#pragma unroll
    for (int g = 0; g < 16; ++g) {
        float v0 = a[g], v1 = a[g | 16];
        float o0 = c * v0 - s * v1;
        float o1 = s * v0 + c * v1;
        if (g & 1) { a[g] = o1; a[g | 16] = o0; }
        else       { a[g] = o0; a[g | 16] = o1; }
    }
}
// Fused RY+CNOT lane gate: tgt = lane bit of MASK, ctrl = lane bit of 2*MASK.
template <int MASK>
__device__ __forceinline__ void lane_gate32(float (&a)[32], float s, float c, int lane) {
    const int tau = (lane & MASK) ? 1 : 0;
    const int gam = (lane & (MASK << 1)) ? 1 : 0;
    const float A = gam ? (tau ? -s : s) : c;
    const float B = gam ? c : (tau ? s : -s);
#pragma unroll
    for (int r = 0; r < 32; ++r) {
        float p = xor_lanes<MASK>(a[r], lane);
        a[r] = A * a[r] + B * p;
    }
}
// RY-only lane gate on lane bit of MASK.
template <int MASK>
__device__ __forceinline__ void lane_ry32(float (&a)[32], float s, float c, int lane) {
    const int tau = (lane & MASK) ? 1 : 0;
    const float A = c, B = tau ? s : -s;
#pragma unroll
    for (int r = 0; r < 32; ++r) {
        float p = xor_lanes<MASK>(a[r], lane);
        a[r] = A * a[r] + B * p;
    }
}
// Lane gate, tgt = lane bit of MASK, ctrl = reg bit 0.
template <int MASK>
__device__ __forceinline__ void lane_gate32_regctrl(float (&a)[32], float s, float c,
                                                    int lane, int tau) {
    const float A0 = c,            B0 = tau ? s : -s;
    const float A1 = tau ? -s : s, B1 = c;
#pragma unroll
    for (int r = 0; r < 32; ++r) {
        float p = xor_lanes<MASK>(a[r], lane);
        float A = (r & 1) ? A1 : A0;
        float B = (r & 1) ? B1 : B0;
        a[r] = A * a[r] + B * p;
    }
}

// Identity chunked transpose (chunk = reg bit 4): swap reg bits0..3 <-> w.
#define IDT_TRANSPOSE(a, lds, lane, w)                                   \
    _Pragma("unroll")                                                    \
    for (int x = 0; x < 2; ++x) {                                        \
        __syncthreads();                                                 \
        _Pragma("unroll")                                                \
        for (int j = 0; j < 16; ++j)                                     \
            lds[(lane) | ((w) << 6) | (j << 10)] = a[(x << 4) | j];      \
        __syncthreads();                                                 \
        _Pragma("unroll")                                                \
        for (int m = 0; m < 16; ++m)                                     \
            a[(x << 4) | m] = lds[(lane) | (m << 6) | ((w) << 10)];      \
    }

// =========================== Kernel F ===========================
// b0 analytic + b1 q0..14. Span {e9..23}; blk = e0..8. No global reads.
__global__ __launch_bounds__(1024, 2)
void kernF(float* __restrict__ dst, const float* __restrict__ angles) {
    __shared__ float lds[16384];
    __shared__ float s0[24], c0[24], s1[15], c1[15];
    const int tid  = threadIdx.x;
    const int lane = tid & 63;
    const int w    = tid >> 6;
    const int blk  = blockIdx.x;                 // e0..8

    if (tid < 24) {
        float s, c; sincosf(0.5f * angles[tid], &s, &c);
        s0[tid] = s; c0[tid] = c;
    } else if (tid >= 32 && tid < 47) {
        float s, c; sincosf(0.5f * angles[24 + (tid - 32)], &s, &c);
        s1[tid - 32] = s; c1[tid - 32] = c;
    }

    // f10 sim (b0 q0..9) in lds[0..1023]; f bit k = e(14+k), qubit q -> bit 9-q.
    float* f = lds;
    f[tid] = 0.0f;
    __syncthreads();
    if (tid == 0) f[0] = 1.0f;
    __syncthreads();
    if (tid < 512) {
        float s = s0[0], c = c0[0];
        float v0 = f[tid], v1 = f[tid | 512];
        f[tid] = c * v0 - s * v1;
        f[tid | 512] = s * v0 + c * v1;
    }
    __syncthreads();
    for (int q = 1; q <= 9; ++q) {
        int bt = 9 - q;
        if (tid < 256) {
            float s = s0[q], c = c0[q];
            int lo  = tid & ((1 << bt) - 1);
            int r00 = ((tid >> bt) << (bt + 2)) | lo;
            int r01 = r00 | (1 << bt);
            int r10 = r00 | (2 << bt);
            int r11 = r00 | (3 << bt);
            float v00 = f[r00], v01 = f[r01], v10 = f[r10], v11 = f[r11];
            f[r00] = c * v00 - s * v01;
            f[r01] = s * v00 + c * v01;
            f[r10] = s * v10 + c * v11;
            f[r11] = c * v10 - s * v11;
        }
        __syncthreads();
    }

    float gfix = 1.0f;
#pragma unroll
    for (int j = 0; j < 8; ++j) {                // q23..q16: blk-only bits
        int x = ((blk >> j) ^ (blk >> (j + 1))) & 1;
        gfix *= x ? s0[23 - j] : c0[23 - j];
    }
    const float fval = f[w | (lane << 4)];
    const int b8 = (blk >> 8) & 1;
    const int w0 = w & 1;                        // e14

    float a[32];
#pragma unroll
    for (int r = 0; r < 32; ++r) {
        const int r0 = r & 1, r1 = (r >> 1) & 1, r2 = (r >> 2) & 1,
                  r3 = (r >> 3) & 1, r4 = (r >> 4) & 1;
        float g = gfix;
        g *= (b8 ^ r0) ? s0[15] : c0[15];
        g *= (r0 ^ r1) ? s0[14] : c0[14];
        g *= (r1 ^ r2) ? s0[13] : c0[13];
        g *= (r2 ^ r3) ? s0[12] : c0[12];
        g *= (r3 ^ r4) ? s0[11] : c0[11];
        g *= (r4 ^ w0) ? s0[10] : c0[10];
        a[r] = fval * g;
    }

    lane_ry32<32>(a, s1[0], c1[0], lane);        // q0 RY e23
    lane_gate32<16>(a, s1[1], c1[1], lane);      // q1
    lane_gate32<8>(a, s1[2], c1[2], lane);       // q2
    lane_gate32<4>(a, s1[3], c1[3], lane);       // q3
    lane_gate32<2>(a, s1[4], c1[4], lane);       // q4
    lane_gate32<1>(a, s1[5], c1[5], lane);       // q5

    IDT_TRANSPOSE(a, lds, lane, w)               // T_F (chunk e13@r4)

    pair_bit32<3>(a, s1[6], c1[6], lane & 1);    // q6: tgt e17, ctrl e18
    quad_gate32<2>(a, s1[7], c1[7]);             // q7
    quad_gate32<1>(a, s1[8], c1[8]);             // q8
    quad_gate32<0>(a, s1[9], c1[9]);             // q9
    pair_ctrl_reg0(a, s1[10], c1[10]);           // q10: tgt e13(r4), ctrl e14(r0)

    IDT_TRANSPOSE(a, lds, lane, w)               // T2_F (chunk e13)

    quad_gate32<3>(a, s1[11], c1[11]);           // q11
    quad_gate32<2>(a, s1[12], c1[12]);           // q12
    quad_gate32<1>(a, s1[13], c1[13]);           // q13
    quad_gate32<0>(a, s1[14], c1[14]);           // q14

#pragma unroll
    for (int m = 0; m < 32; ++m)
        dst[((size_t)blk << 15) | lane | (w << 6) | ((m & 15) << 10)
            | ((m >> 4) << 14)] = a[m];
}

// =========================== Kernel A ===========================
// b1 q15..23 + b2 q0..5. Span {e0..8}u{e18..23}; blk = e9..17.
__global__ __launch_bounds__(1024)
void kernA(const float* __restrict__ src, float* __restrict__ dst,
           const float* __restrict__ angles) {
    __shared__ float lds[16384];
    __shared__ float scs[15], scc[15];
    const int tid  = threadIdx.x;
    const int lane = tid & 63;
    const int w    = tid >> 6;
    const int blk  = blockIdx.x;                 // e9..17

    if (tid < 9) {          // b1 q15..23
        float s, c; sincosf(0.5f * angles[24 + 15 + tid], &s, &c);
        scs[tid] = s; scc[tid] = c;
    } else if (tid >= 16 && tid < 22) {          // b2 q0..5
        float s, c; sincosf(0.5f * angles[48 + (tid - 16)], &s, &c);
        scs[9 + tid - 16] = s; scc[9 + tid - 16] = c;
    }

    float a[32];
    const int hi4 = blk >> 5, lo4 = blk & 15, b13 = (blk >> 4) & 1;
#pragma unroll
    for (int r = 0; r < 32; ++r) {
        int Fblk = ((r >> 4) & 1) | (w << 1) | ((r & 15) << 5);
        a[r] = src[((size_t)Fblk << 15) | lane | (hi4 << 6) | (lo4 << 10)
                   | (b13 << 14)];
    }
    __syncthreads();

    pair_bit32<3>(a, scs[0], scc[0], blk & 1);   // q15: tgt e8, ctrl e9 (diag)
    quad_gate32<2>(a, scs[1], scc[1]);           // q16
    quad_gate32<1>(a, scs[2], scc[2]);           // q17
    quad_gate32<0>(a, scs[3], scc[3]);           // q18

    IDT_TRANSPOSE(a, lds, lane, w)               // T_A (chunk e0@r4)

    pair_bit32<3>(a, scs[4], scc[4], w & 1);     // q19: tgt e4, ctrl e5
    quad_gate32<2>(a, scs[5], scc[5]);           // q20
    quad_gate32<1>(a, scs[6], scc[6]);           // q21
    quad_gate32<0>(a, scs[7], scc[7]);           // q22
    pair_ctrl_reg0(a, scs[8], scc[8]);           // q23: tgt e0(r4), ctrl e1(r0)

    lane_ry32<32>(a, scs[9], scc[9], lane);      // b2 q0 RY e23
    lane_gate32<16>(a, scs[10], scc[10], lane);  // q1
    lane_gate32<8>(a, scs[11], scc[11], lane);   // q2
    lane_gate32<4>(a, scs[12], scc[12], lane);   // q3
    lane_gate32<2>(a, scs[13], scc[13], lane);   // q4
    lane_gate32<1>(a, scs[14], scc[14], lane);   // q5

    // T_A2 + write (chunk e0 = reg bit 4), swizzled; hoisted constants.
    const int W37 = (w & 7) << 2;
    const int LW  = (lane & 31) ^ W37;
    const int HA  = (((lane >> 5) & 1) << 5) | (((w >> 3) & 1) << 6) | (W37 << 7);
    const int RW  = W37 ^ (lane & 31);
    const int HR  = (((w >> 3) & 1) << 5) | (((lane >> 5) & 1) << 6)
                  | ((lane & 31) << 7);
    const size_t DA = ((size_t)blk << 15) | (size_t)lane | ((size_t)w << 11);
#pragma unroll
    for (int x = 0; x < 2; ++x) {
        __syncthreads();
#pragma unroll
        for (int jj = 0; jj < 16; ++jj) {        // regs (x<<4)|jj; jj = e1..4
            int j2 = jj >> 2;
            int h = (LW ^ j2) | HA | (j2 << 7)
                  | ((jj & 1) << 12) | (((jj >> 1) & 1) << 13);
            lds[h] = a[(x << 4) | jj];
        }
        __syncthreads();
#pragma unroll
        for (int mm = 0; mm < 16; ++mm) {        // L2 regs: mm=(e1,e2,e18,e19)
            int m2 = ((mm >> 2) & 1) | (((mm >> 3) & 1) << 1);
            int h = (RW ^ m2) | HR | ((mm & 1) << 12) | (((mm >> 1) & 1) << 13);
            float v = lds[h];
            dst[DA | (x << 6) | ((mm & 1) << 7) | (((mm >> 1) & 1) << 8)
                | (((mm >> 2) & 1) << 9) | (((mm >> 3) & 1) << 10)] = v;
        }
    }
}

// =========================== Kernel B ===========================
// b2 q6..20. Span {e3..17}; blk: [0..2]=e0..2, [3]=e18, [4]=e19, [5..8]=e20..23.
__global__ __launch_bounds__(1024)
void kernB(const float* __restrict__ src, float* __restrict__ dst,
           const float* __restrict__ angles) {
    __shared__ float lds[16384];
    __shared__ float scs[15], scc[15];
    const int tid  = threadIdx.x;
    const int lane = tid & 63;
    const int w    = tid >> 6;
    const int blk  = blockIdx.x;

    if (tid < 15) {                              // b2 q6..20
        float s, c; sincosf(0.5f * angles[48 + 6 + tid], &s, &c);
        scs[tid] = s; scc[tid] = c;
    }

    float a[32];
    const int fixedA = ((blk & 1) << 6) | (((blk >> 1) & 1) << 7)
                     | (((blk >> 2) & 1) << 8) | (((blk >> 3) & 1) << 9)
                     | (((blk >> 4) & 1) << 10) | ((blk >> 5) << 11);
#pragma unroll
    for (int r = 0; r < 32; ++r) {
        int Ablk = w | (r << 4);                 // e9..12=w, e13..17=r
        a[r] = src[((size_t)Ablk << 15) | lane | fixedA];
    }
    __syncthreads();

    pair_bit32<4>(a, scs[0], scc[0], (blk >> 3) & 1);  // q6: tgt e17, ctrl e18 diag
    quad_gate32<3>(a, scs[1], scc[1]);           // q7
    quad_gate32<2>(a, scs[2], scc[2]);           // q8
    quad_gate32<1>(a, scs[3], scc[3]);           // q9
    quad_gate32<0>(a, scs[4], scc[4]);           // q10

    IDT_TRANSPOSE(a, lds, lane, w)               // T1_B (chunk e17@r4)

    pair_bit32<3>(a, scs[5], scc[5], w & 1);     // q11: tgt e12, ctrl e13
    quad_gate32<2>(a, scs[6], scc[6]);           // q12
    quad_gate32<1>(a, scs[7], scc[7]);           // q13
    quad_gate32<0>(a, scs[8], scc[8]);           // q14
    lane_gate32_regctrl<32>(a, scs[9], scc[9], lane, (lane >> 5) & 1); // q15
    lane_gate32<16>(a, scs[10], scc[10], lane);  // q16
    lane_gate32<8>(a, scs[11], scc[11], lane);   // q17
    lane_gate32<4>(a, scs[12], scc[12], lane);   // q18
    lane_gate32<2>(a, scs[13], scc[13], lane);   // q19
    lane_gate32<1>(a, scs[14], scc[14], lane);   // q20

    // T_B2 + write (chunk e9 = reg bit 0), swizzled; hoisted constants.
    const int WB = (lane & 7)
                 | ((((lane >> 3) & 1) ^ ((w >> 2) & 1)) << 3)
                 | ((((lane >> 4) & 1) ^ ((w >> 3) & 1)) << 4)
                 | (((lane >> 5) & 1) << 5)
                 | (((w >> 2) & 1) << 6) | (((w >> 3) & 1) << 7)
                 | ((w & 1) << 12) | (((w >> 1) & 1) << 13);
    const int RB = (lane & 7)
                 | (((w & 1) ^ ((lane >> 3) & 1)) << 3)
                 | ((((w >> 1) & 1) ^ ((lane >> 4) & 1)) << 4)
                 | (((w >> 2) & 1) << 5)
                 | (((lane >> 3) & 1) << 6) | (((lane >> 4) & 1) << 7)
                 | (((lane >> 5) & 1) << 8) | (((w >> 3) & 1) << 13);
    const size_t DB = ((size_t)blk << 15) | (size_t)lane | ((size_t)(w & 7) << 6)
                    | ((size_t)((w >> 3) & 1) << 14);
#pragma unroll
    for (int x = 0; x < 2; ++x) {
        __syncthreads();
#pragma unroll
        for (int jj = 0; jj < 16; ++jj) {        // regs (jj<<1)|x; jj: e10..12, e17
            int h = WB | (((jj >> 3) & 1) << 8) | ((jj & 7) << 9);
            lds[h] = a[(jj << 1) | x];
        }
        __syncthreads();
#pragma unroll
        for (int mm = 0; mm < 16; ++mm) {        // L2 regs (mm<<1)|x; mm: e10..12, e13
            int h = RB | ((mm & 7) << 9) | (((mm >> 3) & 1) << 12);
            float v = lds[h];
            dst[DB | (x << 9) | ((mm & 7) << 10) | (((mm >> 3) & 1) << 13)] = v;
        }
    }
}

// =========================== Kernel C ===========================
// b2 q21..23 + b3 q0..8. Span {e0..5}u{e15..23}; blk = e6..14.
__global__ __launch_bounds__(1024)
void kernC(const float* __restrict__ src, float* __restrict__ dst,
           const float* __restrict__ angles) {
    __shared__ float lds[16384];
    __shared__ float scs[12], scc[12];
    const int tid  = threadIdx.x;
    const int lane = tid & 63;
    const int w    = tid >> 6;
    const int blk  = blockIdx.x;                 // e6..14

    if (tid < 3) {                               // b2 q21..23
        float s, c; sincosf(0.5f * angles[48 + 21 + tid], &s, &c);
        scs[tid] = s; scc[tid] = c;
    } else if (tid >= 8 && tid < 17) {           // b3 q0..8
        float s, c; sincosf(0.5f * angles[72 + (tid - 8)], &s, &c);
        scs[3 + tid - 8] = s; scc[3 + tid - 8] = c;
    }

    float a[32];
    const int fixedB = ((blk & 7) << 6) | (((blk >> 3) & 15) << 9)
                     | (((blk >> 7) & 1) << 13) | (((blk >> 8) & 1) << 14);
#pragma unroll
    for (int r = 0; r < 32; ++r) {
        int Bblk = (r & 31) | (w << 5);          // e0..2,e18,e19 = r; e20..23 = w
        a[r] = src[((size_t)Bblk << 15) | lane | fixedB];
    }
    __syncthreads();

    pair_bit32<2>(a, scs[0], scc[0], lane & 1);  // q21: tgt e2, ctrl e3 (lane0)
    quad_gate32<1>(a, scs[1], scc[1]);           // q22
    quad_gate32<0>(a, scs[2], scc[2]);           // q23

    IDT_TRANSPOSE(a, lds, lane, w)               // T_C (chunk e19@r4)

    pair_bit32<3>(a, scs[3], scc[3], 0);         // b3 q0: RY tgt e23
    quad_gate32<2>(a, scs[4], scc[4]);           // q1
    quad_gate32<1>(a, scs[5], scc[5]);           // q2
    quad_gate32<0>(a, scs[6], scc[6]);           // q3
    pair_ctrl_reg0(a, scs[7], scc[7]);           // q4: tgt e19(r4), ctrl e20(r0)

    // T_C3 (chunk e19 = reg bit 4), swizzled; hoisted constants.
    const int WC = (lane & 7)
                 | ((((lane >> 3) & 1) ^ (w & 1)) << 3)
                 | ((((lane >> 4) & 1) ^ ((w >> 1) & 1)) << 4)
                 | (((lane >> 5) & 1) << 5)
                 | (((lane >> 3) & 1) << 6) | (((lane >> 4) & 1) << 7)
                 | (((w >> 3) & 1) << 8) | (((w >> 2) & 1) << 9);
    const int RC = ((lane >> 3) & 7) | ((lane & 1) << 3) | (((lane >> 1) & 1) << 4)
                 | (((lane >> 2) & 1) << 9) | (w << 10);
#pragma unroll
    for (int x = 0; x < 2; ++x) {
        __syncthreads();
#pragma unroll
        for (int jj = 0; jj < 16; ++jj) {        // regs (x<<4)|jj; jj = e20..23
            lds[WC | (jj << 10)] = a[(x << 4) | jj];
        }
        __syncthreads();
#pragma unroll
        for (int mm = 0; mm < 16; ++mm) {        // L2 regs (x<<4)|mm; mm = e15..18
            int h = (RC ^ ((mm & 1) << 3) ^ ((((mm >> 1) & 1)) << 4))
                  | (((mm >> 2) & 1) << 5) | ((mm & 1) << 6)
                  | (((mm >> 1) & 1) << 7) | (((mm >> 3) & 1) << 8);
            a[(x << 4) | mm] = lds[h];
        }
    }

    quad_gate32<3>(a, scs[8], scc[8]);           // q5: tgt e18 ctrl e19
    quad_gate32<2>(a, scs[9], scc[9]);           // q6
    quad_gate32<1>(a, scs[10], scc[10]);         // q7
    quad_gate32<0>(a, scs[11], scc[11]);         // q8

#pragma unroll
    for (int m = 0; m < 32; ++m)
        dst[((size_t)blk << 15) | lane | ((m & 15) << 6) | ((m >> 4) << 10)
            | (w << 11)] = a[m];
}

// =========================== Kernel D ===========================
// b3 q9..23 + SQUARE. Span {e0..14}; blk = e15..23. Read hC; write STANDARD.
__global__ __launch_bounds__(1024, 2)
void kernD(const float* __restrict__ src, float* __restrict__ dst,
           const float* __restrict__ angles) {
    __shared__ float lds[16384];
    __shared__ float scs[15], scc[15];
    const int tid  = threadIdx.x;
    const int lane = tid & 63;
    const int w    = tid >> 6;
    const int blk  = blockIdx.x;                 // e15..23

    if (tid < 15) {                              // b3 q9..23
        float s, c; sincosf(0.5f * angles[72 + 9 + tid], &s, &c);
        scs[tid] = s; scc[tid] = c;
    }

    float a[32];
#pragma unroll
    for (int r = 0; r < 32; ++r) {
        int Cblk = w | (r << 4);                 // e6..9=w, e10..14=r
        a[r] = src[((size_t)Cblk << 15) | lane | (blk << 6)];
    }
    __syncthreads();

    pair_bit32<4>(a, scs[0], scc[0], blk & 1);   // q9: tgt e14, ctrl e15 diag
    quad_gate32<3>(a, scs[1], scc[1]);           // q10
    quad_gate32<2>(a, scs[2], scc[2]);           // q11
    quad_gate32<1>(a, scs[3], scc[3]);           // q12
    quad_gate32<0>(a, scs[4], scc[4]);           // q13

    IDT_TRANSPOSE(a, lds, lane, w)               // T1_D (chunk e14@r4)

    pair_bit32<3>(a, scs[5], scc[5], w & 1);     // q14: tgt e9, ctrl e10
    quad_gate32<2>(a, scs[6], scc[6]);           // q15
    quad_gate32<1>(a, scs[7], scc[7]);           // q16
    quad_gate32<0>(a, scs[8], scc[8]);           // q17
    lane_gate32_regctrl<32>(a, scs[9], scc[9], lane, (lane >> 5) & 1); // q18
    lane_gate32<16>(a, scs[10], scc[10], lane);  // q19
    lane_gate32<8>(a, scs[11], scc[11], lane);   // q20
    lane_gate32<4>(a, scs[12], scc[12], lane);   // q21
    lane_gate32<2>(a, scs[13], scc[13], lane);   // q22
    lane_gate32<1>(a, scs[14], scc[14], lane);   // q23

#pragma unroll
    for (int r = 0; r < 32; ++r) a[r] *= a[r];   // SQUARE

#pragma unroll
    for (int m = 0; m < 32; ++m)
        dst[((size_t)blk << 15) | ((m >> 4) << 14) | (w << 10) | ((m & 15) << 6)
            | lane] = a[m];
}

extern "C" void kernel_launch(void* const* d_in, const int* in_sizes, int n_in,
                              void* d_out, int out_size, void* d_ws, size_t ws_size,
                              hipStream_t stream) {
    const float* angles = (const float*)d_in[0];
    float* out = (float*)d_out;
    float* ws  = (float*)d_ws;

    kernF<<<512, 1024, 0, stream>>>(out, angles);        // -> out (hF)
    kernA<<<512, 1024, 0, stream>>>(out, ws, angles);    // out -> ws (hA)
    kernB<<<512, 1024, 0, stream>>>(ws, out, angles);    // ws -> out (hB)
    kernC<<<512, 1024, 0, stream>>>(out, ws, angles);    // out -> ws (hC)
    kernD<<<512, 1024, 0, stream>>>(ws, out, angles);    // ws -> out (std)
}